// Round 1
// baseline (508.646 us; speedup 1.0000x reference)
//
#include <hip/hip_runtime.h>
#include <math.h>

#define N_NODES 256
#define T_DIM   30000
#define H_DIM   512
#define L_DIM   256

#define KC      944   // per-split K chunk (multiple of 16; 32*944 >= 30000)
#define SPLITK  32

// ---------------- P = I + C ----------------
__global__ void k_init_P(float* P) {
    int t = blockIdx.x * blockDim.x + threadIdx.x; // 65536 threads
    P[t] = ((t >> 8) == (t & 255)) ? 1.0f : 0.0f;
}

__global__ void k_count_edges(const int* __restrict__ idx, int E, float* P) {
    int e = blockIdx.x * blockDim.x + threadIdx.x;
    if (e < E) {
        int s = idx[e];
        int d = idx[E + e];
        atomicAdd(&P[d * N_NODES + s], 1.0f);
    }
}

__global__ void k_zero(float* p, int n) {
    int t = blockIdx.x * blockDim.x + threadIdx.x;
    if (t < n) p[t] = 0.0f;
}

// ---------------- big GEMM: Y1 = x @ Ws1a ----------------
// x [256,30000] row-major, W [30000,512] row-major.
// grid (4,2,SPLITK): 128x128 output tile per block, K split.
template<bool ATOMIC>
__global__ __launch_bounds__(256)
void k_gemm_big(const float* __restrict__ x, const float* __restrict__ W,
                float* __restrict__ outp) {
    __shared__ float xs[16 * 140]; // [k][r] transposed, pad 140
    __shared__ float ws[16 * 132]; // [k][c], pad 132

    const int t  = threadIdx.x;
    const int bx = blockIdx.x;   // col tile 0..3
    const int by = blockIdx.y;   // row tile 0..1
    const int z  = blockIdx.z;   // K split 0..31
    const int rowBase = by * 128;
    const int colBase = bx * 128;
    const int kb0  = z * KC;
    const int kend = min(kb0 + KC, T_DIM);
    const int nchunk = (kend - kb0) >> 4;

    const int lr  = t >> 2;          // 0..63 (row for x load)
    const int lkq = (t & 3) * 4;     // 0,4,8,12 (k offset for x load)
    const int wkk = t >> 5;          // 0..7 (k row for W load)
    const int wcq = (t & 31) * 4;    // 0..124 (col offset for W load)
    const int tx  = t & 15, ty = t >> 4;

    float acc[8][8];
    #pragma unroll
    for (int i = 0; i < 8; ++i)
        #pragma unroll
        for (int j = 0; j < 8; ++j) acc[i][j] = 0.0f;

    float4 xa, xb, wa, wb;
    {   // prefetch chunk 0
        const float* xp = x + (size_t)(rowBase + lr) * T_DIM + kb0 + lkq;
        xa = *(const float4*)xp;
        xb = *(const float4*)(xp + (size_t)64 * T_DIM);
        const float* wp = W + (size_t)(kb0 + wkk) * H_DIM + colBase + wcq;
        wa = *(const float4*)wp;
        wb = *(const float4*)(wp + 8 * H_DIM);
    }

    for (int c = 0; c < nchunk; ++c) {
        __syncthreads();
        xs[(lkq + 0) * 140 + lr] = xa.x;
        xs[(lkq + 1) * 140 + lr] = xa.y;
        xs[(lkq + 2) * 140 + lr] = xa.z;
        xs[(lkq + 3) * 140 + lr] = xa.w;
        xs[(lkq + 0) * 140 + lr + 64] = xb.x;
        xs[(lkq + 1) * 140 + lr + 64] = xb.y;
        xs[(lkq + 2) * 140 + lr + 64] = xb.z;
        xs[(lkq + 3) * 140 + lr + 64] = xb.w;
        *(float4*)&ws[wkk * 132 + wcq]       = wa;
        *(float4*)&ws[(wkk + 8) * 132 + wcq] = wb;
        __syncthreads();

        if (c + 1 < nchunk) {   // prefetch next chunk into regs
            int kb = kb0 + (c + 1) * 16;
            const float* xp = x + (size_t)(rowBase + lr) * T_DIM + kb + lkq;
            xa = *(const float4*)xp;
            xb = *(const float4*)(xp + (size_t)64 * T_DIM);
            const float* wp = W + (size_t)(kb + wkk) * H_DIM + colBase + wcq;
            wa = *(const float4*)wp;
            wb = *(const float4*)(wp + 8 * H_DIM);
        }

        #pragma unroll
        for (int kk = 0; kk < 16; ++kk) {
            float a[8], b[8];
            *(float4*)&a[0] = *(const float4*)&xs[kk * 140 + ty * 8];
            *(float4*)&a[4] = *(const float4*)&xs[kk * 140 + ty * 8 + 4];
            *(float4*)&b[0] = *(const float4*)&ws[kk * 132 + tx * 8];
            *(float4*)&b[4] = *(const float4*)&ws[kk * 132 + tx * 8 + 4];
            #pragma unroll
            for (int i = 0; i < 8; ++i)
                #pragma unroll
                for (int j = 0; j < 8; ++j)
                    acc[i][j] = fmaf(a[i], b[j], acc[i][j]);
        }
    }

    float* op = ATOMIC ? outp : outp + (size_t)z * (N_NODES * H_DIM);
    #pragma unroll
    for (int i = 0; i < 8; ++i) {
        int r = rowBase + ty * 8 + i;
        if (ATOMIC) {
            #pragma unroll
            for (int j = 0; j < 8; ++j)
                atomicAdd(&op[r * H_DIM + colBase + tx * 8 + j], acc[i][j]);
        } else {
            *(float4*)&op[r * H_DIM + colBase + tx * 8]     = *(float4*)&acc[i][0];
            *(float4*)&op[r * H_DIM + colBase + tx * 8 + 4] = *(float4*)&acc[i][4];
        }
    }
}

__global__ void k_reduce(const float* __restrict__ Y1p, float* __restrict__ Y1) {
    int i = blockIdx.x * blockDim.x + threadIdx.x; // 131072 threads
    float s = 0.0f;
    #pragma unroll
    for (int z = 0; z < SPLITK; ++z) s += Y1p[(size_t)z * (N_NODES * H_DIM) + i];
    Y1[i] = s;
}

// ---------------- small GEMM: out = act(A[256,K] @ B[K,N] + bias) ----------------
// grid (N/64, 4), 64x64 tile, 4x4 per thread. K in {256,512}, N in {256,512}.
__global__ __launch_bounds__(256)
void k_gemm_small(const float* __restrict__ A, const float* __restrict__ B,
                  const float* __restrict__ bias, float* __restrict__ out,
                  int K, int N, int act) {
    __shared__ float as[64 * 17];
    __shared__ float bs[16 * 68];
    const int t  = threadIdx.x;
    const int c0 = blockIdx.x * 64;
    const int r0 = blockIdx.y * 64;
    const int lr = t >> 2, lkq = (t & 3) * 4;
    const int bkk = t >> 4, bcq = (t & 15) * 4;
    const int tx = t & 15, ty = t >> 4;

    float acc[4][4] = {};
    for (int kb = 0; kb < K; kb += 16) {
        __syncthreads();
        float4 av = *(const float4*)&A[(size_t)(r0 + lr) * K + kb + lkq];
        as[lr * 17 + lkq + 0] = av.x;
        as[lr * 17 + lkq + 1] = av.y;
        as[lr * 17 + lkq + 2] = av.z;
        as[lr * 17 + lkq + 3] = av.w;
        *(float4*)&bs[bkk * 68 + bcq] = *(const float4*)&B[(size_t)(kb + bkk) * N + c0 + bcq];
        __syncthreads();
        #pragma unroll
        for (int kk = 0; kk < 16; ++kk) {
            float a[4], b[4];
            #pragma unroll
            for (int i = 0; i < 4; ++i) a[i] = as[(ty * 4 + i) * 17 + kk];
            *(float4*)&b[0] = *(const float4*)&bs[kk * 68 + tx * 4];
            #pragma unroll
            for (int i = 0; i < 4; ++i)
                #pragma unroll
                for (int j = 0; j < 4; ++j)
                    acc[i][j] = fmaf(a[i], b[j], acc[i][j]);
        }
    }
    #pragma unroll
    for (int i = 0; i < 4; ++i) {
        int r = r0 + ty * 4 + i;
        #pragma unroll
        for (int j = 0; j < 4; ++j) {
            int cc = c0 + tx * 4 + j;
            float v = acc[i][j];
            if (bias) v += bias[cc];
            if (act) v = fmaxf(v, 0.0f);
            out[(size_t)r * N + cc] = v;
        }
    }
}

// ---------------- region scores ----------------
__global__ void k_score(const float* __restrict__ A4, const float* __restrict__ Wc2a,
                        const float* __restrict__ bc2a, const float* __restrict__ Wc2b,
                        const float* __restrict__ bc2b, float* __restrict__ out) {
    int w = threadIdx.x >> 6;
    int lane = threadIdx.x & 63;
    int row = blockIdx.x * 4 + w;
    float s = 0.0f;
    for (int k = lane; k < H_DIM; k += 64) s += A4[(size_t)row * H_DIM + k] * Wc2a[k];
    #pragma unroll
    for (int off = 32; off; off >>= 1) s += __shfl_down(s, off, 64);
    if (lane == 0) {
        float t4 = fmaxf(s + bc2a[0], 0.0f);
        float sc = t4 * Wc2b[0] + bc2b[0];
        out[1 + row] = 1.0f / (1.0f + expf(-sc));
    }
}

// ---------------- dementia head ----------------
__global__ void k_dementia(const float* __restrict__ feat, const float* __restrict__ Wd,
                           const float* __restrict__ bd, float* __restrict__ out) {
    __shared__ float red[16];
    int t = threadIdx.x; // 1024
    float s = 0.0f;
    for (int e = t; e < N_NODES * L_DIM; e += 1024) s += feat[e] * Wd[e];
    #pragma unroll
    for (int off = 32; off; off >>= 1) s += __shfl_down(s, off, 64);
    if ((t & 63) == 0) red[t >> 6] = s;
    __syncthreads();
    if (t == 0) {
        float tot = 0.0f;
        #pragma unroll
        for (int i = 0; i < 16; ++i) tot += red[i];
        out[0] = 1.0f / (1.0f + expf(-(tot + bd[0])));
    }
}

extern "C" void kernel_launch(void* const* d_in, const int* in_sizes, int n_in,
                              void* d_out, int out_size, void* d_ws, size_t ws_size,
                              hipStream_t stream) {
    const float* x    = (const float*)d_in[0];
    const int*   idx  = (const int*)d_in[1];
    const float* Ws1a = (const float*)d_in[3];
    const float* bs1a = (const float*)d_in[4];
    const float* Ws1b = (const float*)d_in[5];
    const float* bs1b = (const float*)d_in[6];
    const float* Ws2a = (const float*)d_in[7];
    const float* bs2a = (const float*)d_in[8];
    const float* Ws2b = (const float*)d_in[9];
    const float* bs2b = (const float*)d_in[10];
    const float* Wc1a = (const float*)d_in[11];
    const float* bc1a = (const float*)d_in[12];
    const float* Wc1b = (const float*)d_in[13];
    const float* bc1b = (const float*)d_in[14];
    const float* Wc2a = (const float*)d_in[15];
    const float* bc2a = (const float*)d_in[16];
    const float* Wc2b = (const float*)d_in[17];
    const float* bc2b = (const float*)d_in[18];
    const float* Wd   = (const float*)d_in[19];
    const float* bd   = (const float*)d_in[20];
    float* out = (float*)d_out;
    const int E = in_sizes[1] / 2;

    float* w    = (float*)d_ws;
    float* P    = w;                  // 65536
    float* Y1   = P + 65536;          // 131072
    float* bufA = Y1 + 131072;        // 131072
    float* bufB = bufA + 131072;      // 131072
    float* feat = bufB + 131072;      // 65536
    float* Y1p  = feat + 65536;       // SPLITK * 131072
    const size_t need_full = (size_t)(65536 + 3 * 131072 + 65536 + SPLITK * 131072) * 4;
    const bool partials = ws_size >= need_full;

    // adjacency P = I + C
    k_init_P<<<256, 256, 0, stream>>>(P);
    k_count_edges<<<(E + 255) / 256, 256, 0, stream>>>(idx, E, P);

    // Y1 = x @ Ws1a   (the only big GEMM; P@(x@W) == (P@x)@W)
    if (partials) {
        k_gemm_big<false><<<dim3(4, 2, SPLITK), 256, 0, stream>>>(x, Ws1a, Y1p);
        k_reduce<<<512, 256, 0, stream>>>(Y1p, Y1);
    } else {
        k_zero<<<512, 256, 0, stream>>>(Y1, N_NODES * H_DIM);
        k_gemm_big<true><<<dim3(4, 2, SPLITK), 256, 0, stream>>>(x, Ws1a, Y1);
    }

    // featurizer conv1: t1 = relu(P@Y1 + bs1a); h1r = relu(t1@Ws1b + bs1b)
    k_gemm_small<<<dim3(8, 4), 256, 0, stream>>>(P, Y1, bs1a, bufA, 256, 512, 1);
    k_gemm_small<<<dim3(8, 4), 256, 0, stream>>>(bufA, Ws1b, bs1b, bufB, 512, 512, 1);
    // featurizer conv2: A2 = P@h1r; t2 = relu(A2@Ws2a + bs2a); feat = t2@Ws2b + bs2b
    k_gemm_small<<<dim3(8, 4), 256, 0, stream>>>(P, bufB, nullptr, bufA, 256, 512, 0);
    k_gemm_small<<<dim3(4, 4), 256, 0, stream>>>(bufA, Ws2a, bs2a, bufB, 512, 256, 1);
    k_gemm_small<<<dim3(4, 4), 256, 0, stream>>>(bufB, Ws2b, bs2b, feat, 256, 256, 0);
    // scorer conv1: A3 = P@feat; t3 = relu(A3@Wc1a + bc1a); s1r = relu(t3@Wc1b + bc1b)
    k_gemm_small<<<dim3(4, 4), 256, 0, stream>>>(P, feat, nullptr, bufA, 256, 256, 0);
    k_gemm_small<<<dim3(8, 4), 256, 0, stream>>>(bufA, Wc1a, bc1a, bufB, 256, 512, 1);
    k_gemm_small<<<dim3(8, 4), 256, 0, stream>>>(bufB, Wc1b, bc1b, bufA, 512, 512, 1);
    // scorer conv2: A4 = P@s1r; region = sigmoid(relu(A4@Wc2a + bc2a)*Wc2b + bc2b)
    k_gemm_small<<<dim3(8, 4), 256, 0, stream>>>(P, bufA, nullptr, bufB, 256, 512, 0);
    k_score<<<64, 256, 0, stream>>>(bufB, Wc2a, bc2a, Wc2b, bc2b, out);
    // dementia head
    k_dementia<<<1, 1024, 0, stream>>>(feat, Wd, bd, out);
}